// Round 8
// baseline (2115.142 us; speedup 1.0000x reference)
//
#include <hip/hip_runtime.h>

typedef __attribute__((ext_vector_type(4))) float  f32x4;
typedef __attribute__((ext_vector_type(8))) short  short8;
typedef __attribute__((ext_vector_type(4))) int    i32x4;
typedef __attribute__((ext_vector_type(2))) int    i32x2;

#define LOG2E 1.4426950408889634f

__device__ __forceinline__ float fexp2(float x){ float r; asm("v_exp_f32 %0, %1" : "=v"(r) : "v"(x)); return r; }
__device__ __forceinline__ float frcp (float x){ float r; asm("v_rcp_f32 %0, %1" : "=v"(r) : "v"(x)); return r; }
__device__ __forceinline__ float fsigmoid(float x){ return frcp(1.f + fexp2(-LOG2E*x)); }
__device__ __forceinline__ float ftanhf (float x){ return 1.f - 2.f*frcp(1.f + fexp2(2.f*LOG2E*x)); }

__device__ __forceinline__ unsigned short f2bf(float f){
  unsigned u = __builtin_bit_cast(unsigned, f);
  u = u + 0x7FFFu + ((u >> 16) & 1u);
  return (unsigned short)(u >> 16);
}
__device__ __forceinline__ float bf2f(unsigned short h){
  unsigned u = ((unsigned)h) << 16;
  return __builtin_bit_cast(float, u);
}

// ---------------- prep kernels ----------------
__global__ void cast_f32_bf16(const float* __restrict__ s, unsigned short* __restrict__ d, int n4){
  int i = blockIdx.x * 256 + threadIdx.x;
  int stride = gridDim.x * 256;
  for (; i < n4; i += stride){
    float4 f = ((const float4*)s)[i];
    uint2 o;
    o.x = (unsigned)f2bf(f.x) | ((unsigned)f2bf(f.y) << 16);
    o.y = (unsigned)f2bf(f.z) | ((unsigned)f2bf(f.w) << 16);
    ((uint2*)d)[i] = o;
  }
}

__global__ void pack_w1(const float* __restrict__ W1, unsigned short* __restrict__ d){
  int i = blockIdx.x * 256 + threadIdx.x;   // 0..32767
  int r = i >> 9, c = i & 511;
  float v = 0.f;
  if (r < 10) v = W1[r * 1024 + c];
  else if (r >= 16 && r < 26) v = W1[(r - 16) * 1024 + 512 + c];
  d[i] = f2bf(v);
}

__global__ void pack_bias(const float* __restrict__ bif, const float* __restrict__ bhf,
                          const float* __restrict__ bib, const float* __restrict__ bhb,
                          float* __restrict__ d){
  int i = blockIdx.x * 1024 + threadIdx.x;
  if (i < 1024) d[i] = bif[i] + bhf[i];
  else          d[i] = bib[i - 1024] + bhb[i - 1024];
}

// ---------------- generic bf16 GEMM: C[M,N] = A[M,K] @ B[N,K]^T (+bias) ----------------
// omode: 0 = f32 out, 1 = bf16 out, 2 = bf16 scan-layout scatter (xgp[d][g][t][b][u][gate])
__global__ __launch_bounds__(256) void gemm_abt(
    const unsigned short* __restrict__ A, long lda, long sAz,
    const unsigned short* __restrict__ B, long ldb, long sBz,
    const float* __restrict__ bias,
    void* __restrict__ Cv, long ldc, long sCz,
    int M, int N, int K, int omode)
{
  __shared__ __align__(16) unsigned short As[128 * 40];
  __shared__ __align__(16) unsigned short Bs[128 * 40];
  const int tid = threadIdx.x;
  const int m0 = blockIdx.y * 128;
  const int n0 = blockIdx.x * 128;
  const long z = blockIdx.z;
  A += z * sAz; B += z * sBz;
  const int w = tid >> 6, l = tid & 63;
  const int wm = (w >> 1) * 64, wn = (w & 1) * 64;
  const int lm = l & 15, lq = l >> 4;
  f32x4 acc[4][4] = {};
  const int sr = tid >> 1;
  const int sk = (tid & 1) * 16;
  const unsigned short* Aptr = A + (long)(m0 + sr) * lda + sk;
  const unsigned short* Bptr = B + (long)(n0 + sr) * ldb + sk;
  const bool bvalid = (n0 + sr) < N;
  const int KB = K >> 5;
  for (int kb = 0; kb < KB; ++kb){
    i32x4 av0 = *(const i32x4*)(Aptr);
    i32x4 av1 = *(const i32x4*)(Aptr + 8);
    i32x4 bv0 = {0,0,0,0}, bv1 = {0,0,0,0};
    if (bvalid){ bv0 = *(const i32x4*)(Bptr); bv1 = *(const i32x4*)(Bptr + 8); }
    Aptr += 32; Bptr += 32;
    __syncthreads();
    *(i32x4*)&As[sr * 40 + sk] = av0;  *(i32x4*)&As[sr * 40 + sk + 8] = av1;
    *(i32x4*)&Bs[sr * 40 + sk] = bv0;  *(i32x4*)&Bs[sr * 40 + sk + 8] = bv1;
    __syncthreads();
    const int koff = lq * 8;
    short8 af[4], bf[4];
    #pragma unroll
    for (int mt = 0; mt < 4; ++mt) af[mt] = *(short8*)&As[(wm + mt * 16 + lm) * 40 + koff];
    #pragma unroll
    for (int nt = 0; nt < 4; ++nt) bf[nt] = *(short8*)&Bs[(wn + nt * 16 + lm) * 40 + koff];
    #pragma unroll
    for (int mt = 0; mt < 4; ++mt)
      #pragma unroll
      for (int nt = 0; nt < 4; ++nt)
        acc[mt][nt] = __builtin_amdgcn_mfma_f32_16x16x32_bf16(af[mt], bf[nt], acc[mt][nt], 0, 0, 0);
  }
  #pragma unroll
  for (int mt = 0; mt < 4; ++mt){
    const int mbase = m0 + wm + mt * 16 + lq * 4;
    #pragma unroll
    for (int nt = 0; nt < 4; ++nt){
      const int n = n0 + wn + nt * 16 + lm;
      if (n < N){
        const float bv = bias ? bias[n] : 0.f;
        #pragma unroll
        for (int r = 0; r < 4; ++r){
          const float v = acc[mt][nt][r] + bv;
          const int m = mbase + r;
          if (omode == 2){
            const int b = m >> 10, tt = m & 1023;
            const int dd = n >> 10, gate = (n >> 8) & 3, unit = n & 255;
            const int gg = unit >> 5, u = unit & 31;
            const long idx = (long)(dd * 8 + gg) * 1048576 + (long)tt * 1024 + b * 128 + u * 4 + gate;
            ((unsigned short*)Cv)[idx] = f2bf(v);
          } else {
            const long idx = z * sCz + (long)m * ldc + n;
            if (omode == 1) ((unsigned short*)Cv)[idx] = f2bf(v);
            else            ((float*)Cv)[idx] = v;
          }
        }
      }
    }
  }
}

// ---------------- LSTM scan v8: per-consumer mailboxes ----------------
// 16 blocks x 256 threads. block = (dir d, 32-unit slice g). Wave w = gate w.
// R7 skeleton (quarter polls + ping-pong + B1/MFMA/B2/gates) with ONE change:
// each producer REPLICATES its h slice into 8 per-consumer mailboxes (ring depth 4,
// dword = tag16<<16 | h bf16), so every exchange line is polled by exactly ONE
// consumer wave instead of 16 -> per-line fan-in (the R7 residual contention) drops
// ~16x. Ring safety: publish(t) by any block implies publish(t-1) by all blocks, so
// blocks are always within 1 step; depth 4 >> 2 needed; tags (unique per t) make
// stale slots unreadable. Dword format also removes the shfl pairing from publish.
// mbox[d][cg(8)][slot(4)][b(8)*256+u(256)] dwords = 512 KB total.
__global__ __launch_bounds__(256) void lstm_scan(
    const unsigned short* __restrict__ xgp,  // [d][g][t][b][u][gate] bf16
    const float* __restrict__ Whh_f, const float* __restrict__ Whh_b,
    unsigned* __restrict__ mbox,             // [2][8][4][2048] tagged dwords
    unsigned short* __restrict__ hcat,       // [8][1024][1024] (cols 0..511 here)
    unsigned short* __restrict__ hT)         // [8][512][1024]
{
  const int d  = blockIdx.x & 1;
  const int g  = blockIdx.x >> 1;          // 0..7
  const int tid = threadIdx.x;
  const int w  = tid >> 6;                 // gate / poll quarter
  const int l  = tid & 63;
  const int lm = l & 15;
  const int lq = l >> 4;
  const float* Whh = d ? Whh_b : Whh_f;

  __shared__ __align__(16) unsigned short hbuf[8 * 264];     // shared [b][264]
  __shared__ __align__(16) unsigned short hbatC[32 * 256];   // [tc][b*32+u]
  __shared__ float gbuf[4][32][9];                           // [gate][j][b pad9]

  // resident B fragments: wave w = gate w; rows w*256 + g*32 + nt*16 + lm; k = kt*32+lq*8
  short8 bfr[2][8];
  #pragma unroll
  for (int nt = 0; nt < 2; ++nt){
    const float* wr = Whh + (long)(w * 256 + g * 32 + nt * 16 + lm) * 256 + lq * 8;
    #pragma unroll
    for (int kt = 0; kt < 8; ++kt){
      float4 f0 = *(const float4*)(wr + kt * 32);
      float4 f1 = *(const float4*)(wr + kt * 32 + 4);
      i32x4 p;
      p.x = (unsigned)f2bf(f0.x) | ((unsigned)f2bf(f0.y) << 16);
      p.y = (unsigned)f2bf(f0.z) | ((unsigned)f2bf(f0.w) << 16);
      p.z = (unsigned)f2bf(f1.x) | ((unsigned)f2bf(f1.y) << 16);
      p.w = (unsigned)f2bf(f1.z) | ((unsigned)f2bf(f1.w) << 16);
      bfr[nt][kt] = __builtin_bit_cast(short8, p);
    }
  }

  const int gb = tid >> 5;        // b (0..7)
  const int gj = tid & 31;        // unit local to slice
  float c_state = 0.f;

  const unsigned short* xbase = xgp + (long)(d * 8 + g) * 1048576 + gb * 128 + gj * 4;
  i32x2 xcur = *(const i32x2*)(xbase + (long)(d ? 1023 : 0) * 1024);

  for (int t = 0; t < 1024; ++t){
    // pipelined bias load for t+1 (plain, compiler-tracked)
    i32x2 xnew;
    {
      const int tn = (t < 1023) ? (t + 1) : t;
      const int t_xn = d ? (1023 - tn) : tn;
      xnew = *(const i32x2*)(xbase + (long)t_xn * 1024);
    }
    f32x4 acc0 = {0.f,0.f,0.f,0.f}, acc1 = {0.f,0.f,0.f,0.f};
    if (t > 0){
      const unsigned tagHi = (unsigned)(0x5C00 + (t - 1)) << 16;
      // own mailbox, slot (t-1)&3; wave quarter = batches 2w,2w+1 (2 KB)
      const char* pb0 = (const char*)(mbox + (((long)(d * 8 + g) * 4 + ((t - 1) & 3)) * 2048))
                        + (2 * w) * 1024 + l * 16;
      const char* pb1 = pb0 + 1024;
      i32x4 a0, a1, b0, b1;
      asm volatile("global_load_dwordx4 %0, %1, off sc0 sc1" : "=v"(a0) : "v"(pb0) : "memory");
      asm volatile("global_load_dwordx4 %0, %1, off sc0 sc1" : "=v"(a1) : "v"(pb1) : "memory");
      asm volatile("global_load_dwordx4 %0, %1, off sc0 sc1" : "=v"(b0) : "v"(pb0) : "memory");
      asm volatile("global_load_dwordx4 %0, %1, off sc0 sc1" : "=v"(b1) : "v"(pb1) : "memory");
      bool useA = false;
      int tries = 0;
      for (;;){
        asm volatile("s_waitcnt vmcnt(2)" : "+v"(a0), "+v"(a1) :: "memory");
        if (__all((int)(((a0.x & 0xFFFF0000u) == tagHi) && ((a0.y & 0xFFFF0000u) == tagHi) &&
                        ((a0.z & 0xFFFF0000u) == tagHi) && ((a0.w & 0xFFFF0000u) == tagHi) &&
                        ((a1.x & 0xFFFF0000u) == tagHi) && ((a1.y & 0xFFFF0000u) == tagHi) &&
                        ((a1.z & 0xFFFF0000u) == tagHi) && ((a1.w & 0xFFFF0000u) == tagHi)))){
          useA = true; break;
        }
        asm volatile("s_waitcnt vmcnt(0)" : "+v"(b0), "+v"(b1) :: "memory");
        if (__all((int)(((b0.x & 0xFFFF0000u) == tagHi) && ((b0.y & 0xFFFF0000u) == tagHi) &&
                        ((b0.z & 0xFFFF0000u) == tagHi) && ((b0.w & 0xFFFF0000u) == tagHi) &&
                        ((b1.x & 0xFFFF0000u) == tagHi) && ((b1.y & 0xFFFF0000u) == tagHi) &&
                        ((b1.z & 0xFFFF0000u) == tagHi) && ((b1.w & 0xFFFF0000u) == tagHi)))){
          useA = false; break;
        }
        if (++tries >= 32768){ useA = false; break; }
        asm volatile("global_load_dwordx4 %0, %1, off sc0 sc1" : "=v"(a0) : "v"(pb0) : "memory");
        asm volatile("global_load_dwordx4 %0, %1, off sc0 sc1" : "=v"(a1) : "v"(pb1) : "memory");
        asm volatile("global_load_dwordx4 %0, %1, off sc0 sc1" : "=v"(b0) : "v"(pb0) : "memory");
        asm volatile("global_load_dwordx4 %0, %1, off sc0 sc1" : "=v"(b1) : "v"(pb1) : "memory");
      }
      // drain stragglers before register reuse / LDS scatter
      asm volatile("s_waitcnt vmcnt(0)" : "+v"(b0), "+v"(b1) :: "memory");
      const i32x4 r0 = useA ? a0 : b0;
      const i32x4 r1 = useA ? a1 : b1;
      // pack 4 units (low halves) into 2 dwords per load
      i32x2 p0, p1;
      p0.x = (int)(((unsigned)r0.x & 0xFFFFu) | ((unsigned)r0.y << 16));
      p0.y = (int)(((unsigned)r0.z & 0xFFFFu) | ((unsigned)r0.w << 16));
      p1.x = (int)(((unsigned)r1.x & 0xFFFFu) | ((unsigned)r1.y << 16));
      p1.y = (int)(((unsigned)r1.z & 0xFFFFu) | ((unsigned)r1.w << 16));
      *(i32x2*)&hbuf[(2 * w)     * 264 + l * 4] = p0;
      *(i32x2*)&hbuf[(2 * w + 1) * 264 + l * 4] = p1;
    }
    __syncthreads();   // B1: hbuf complete (all quarters)
    if (t > 0){
      #pragma unroll
      for (int kt = 0; kt < 8; ++kt){
        short8 af = *(const short8*)&hbuf[(lm & 7) * 264 + kt * 32 + lq * 8];
        acc0 = __builtin_amdgcn_mfma_f32_16x16x32_bf16(af, bfr[0][kt], acc0, 0, 0, 0);
        acc1 = __builtin_amdgcn_mfma_f32_16x16x32_bf16(af, bfr[1][kt], acc1, 0, 0, 0);
      }
    }
    // C[b=lq*4+r][j=nt*16+lm] -> gbuf[w][j][b]
    if (l < 32){
      #pragma unroll
      for (int r = 0; r < 4; ++r){
        gbuf[w][lm][lq * 4 + r]      = acc0[r];
        gbuf[w][16 + lm][lq * 4 + r] = acc1[r];
      }
    }
    __syncthreads();   // B2: gbuf visible; also protects hbuf reuse next step
    {
      const float gi = gbuf[0][gj][gb] + bf2f((unsigned short)((unsigned)xcur.x & 0xFFFFu));
      const float gf = gbuf[1][gj][gb] + bf2f((unsigned short)((unsigned)xcur.x >> 16));
      const float gG = gbuf[2][gj][gb] + bf2f((unsigned short)((unsigned)xcur.y & 0xFFFFu));
      const float go = gbuf[3][gj][gb] + bf2f((unsigned short)((unsigned)xcur.y >> 16));
      c_state = fsigmoid(gf) * c_state + fsigmoid(gi) * ftanhf(gG);
      const float h = fsigmoid(go) * ftanhf(c_state);
      const unsigned short hb16 = f2bf(h);
      // publish FIRST: replicate own dword into all 8 same-direction mailboxes
      const unsigned v = ((unsigned)(0x5C00 + t) << 16) | (unsigned)hb16;
      unsigned* sp = mbox + (((long)(d * 8) * 4 + (t & 3)) * 2048) + gb * 256 + g * 32 + gj;
      #pragma unroll
      for (int cg = 0; cg < 8; ++cg){
        asm volatile("global_store_dword %0, %1, off sc0 sc1" :: "v"(sp), "v"(v) : "memory");
        sp += 8192;   // next consumer mailbox (4 slots * 2048 dwords)
      }
      hbatC[(t & 31) * 256 + tid] = hb16;
    }
    xcur = xnew;
    if ((t & 31) == 31){
      // dump chunk [t-31, t]; all reads are this thread's own hbatC entries
      const int t0 = t - 31;
      const int cb = d ? (1023 - t) : t0;
      unsigned pk[16];
      #pragma unroll
      for (int k = 0; k < 16; ++k){
        const int k0 = d ? (31 - 2 * k) : (2 * k);
        const int k1 = d ? (30 - 2 * k) : (2 * k + 1);
        pk[k] = (unsigned)hbatC[k0 * 256 + tid] | ((unsigned)hbatC[k1 * 256 + tid] << 16);
      }
      unsigned short* hp_ = hT + ((long)(tid >> 5) * 512 + d * 256 + g * 32 + (tid & 31)) * 1024 + cb;
      #pragma unroll
      for (int c = 0; c < 4; ++c){
        i32x4 v4; v4.x = (int)pk[c*4]; v4.y = (int)pk[c*4+1]; v4.z = (int)pk[c*4+2]; v4.w = (int)pk[c*4+3];
        *(i32x4*)(hp_ + c * 8) = v4;
      }
      #pragma unroll
      for (int k = 0; k < 32; ++k){
        const int tp = t0 + k;
        const int t_x = d ? (1023 - tp) : tp;
        hcat[((long)gb * 1024 + t_x) * 1024 + d * 256 + g * 32 + gj] = hbatC[k * 256 + tid];
      }
    }
  }
}

// ---------------- attention scores + softmax ----------------
__global__ __launch_bounds__(256) void attn_scores(
    const float* __restrict__ qk,   // [8192][64]: qp at cols 0..9, kp at cols 16..25
    const float* __restrict__ W2,   // [10]
    const int*   __restrict__ mask, // [8][1024]
    unsigned short* __restrict__ attn) // [8][1024][1024] bf16
{
  const int bt = blockIdx.x;
  const int b = bt >> 10;
  const int tid = threadIdx.x;
  __shared__ float red[256];
  float qv[10], w2[10];
  const float* qrow = qk + (long)bt * 64;
  #pragma unroll
  for (int x = 0; x < 10; ++x){ qv[x] = qrow[x]; w2[x] = W2[x]; }
  float sv[4];
  float smax = -3.4e38f;
  #pragma unroll
  for (int uu = 0; uu < 4; ++uu){
    const int u = tid + uu * 256;
    const float* krow = qk + (long)(b * 1024 + u) * 64 + 16;
    float s = 0.f;
    #pragma unroll
    for (int x = 0; x < 10; ++x) s += w2[x] * ftanhf(qv[x] + krow[x]);
    if (mask[b * 1024 + u] == 0) s = -3.0e38f;
    sv[uu] = s;
    smax = fmaxf(smax, s);
  }
  red[tid] = smax; __syncthreads();
  for (int off = 128; off > 0; off >>= 1){
    if (tid < off) red[tid] = fmaxf(red[tid], red[tid + off]);
    __syncthreads();
  }
  const float mx = red[0]; __syncthreads();
  float ev[4]; float lsum = 0.f;
  #pragma unroll
  for (int uu = 0; uu < 4; ++uu){ ev[uu] = fexp2((sv[uu] - mx) * LOG2E); lsum += ev[uu]; }
  red[tid] = lsum; __syncthreads();
  for (int off = 128; off > 0; off >>= 1){
    if (tid < off) red[tid] = red[tid] + red[tid + off];
    __syncthreads();
  }
  const float inv = frcp(red[0]);
  #pragma unroll
  for (int uu = 0; uu < 4; ++uu)
    attn[(long)bt * 1024 + tid + uu * 256] = f2bf(ev[uu] * inv);
}

// ---------------- launch ----------------
extern "C" void kernel_launch(void* const* d_in, const int* in_sizes, int n_in,
                              void* d_out, int out_size, void* d_ws, size_t ws_size,
                              hipStream_t stream) {
  (void)in_sizes; (void)n_in; (void)out_size; (void)ws_size;
  const float* x     = (const float*)d_in[0];
  const int*   mask  = (const int*)d_in[1];
  const float* Wih_f = (const float*)d_in[3];
  const float* Whh_f = (const float*)d_in[4];
  const float* bih_f = (const float*)d_in[5];
  const float* bhh_f = (const float*)d_in[6];
  const float* Wih_b = (const float*)d_in[7];
  const float* Whh_b = (const float*)d_in[8];
  const float* bih_b = (const float*)d_in[9];
  const float* bhh_b = (const float*)d_in[10];
  const float* W1    = (const float*)d_in[11];
  const float* W2    = (const float*)d_in[12];
  const float* W3    = (const float*)d_in[13];
  const float* b3    = (const float*)d_in[14];

  char* W = (char*)d_ws;
  unsigned short* x_bf    = (unsigned short*)(W + 0);            // 12,582,912
  unsigned short* wihcat  = (unsigned short*)(W + 12582912);     //  3,145,728
  unsigned short* w3bf    = (unsigned short*)(W + 15728640);     //  1,048,576
  unsigned short* w1p     = (unsigned short*)(W + 16777216);     //     65,536
  float*          bc      = (float*)        (W + 16842752);      //      8,192
  unsigned short* xgp     = (unsigned short*)(W + 16850944);     // 33,554,432
  unsigned*       mbox    = (unsigned*)     (W + 50405376);      //    524,288 (ring mailboxes)
  unsigned short* hcat    = (unsigned short*)(W + 67182592);     // 16,777,216
  unsigned short* hT      = (unsigned short*)(W + 83959808);     //  8,388,608
  float*          qk      = (float*)        (W + 92348416);      //  2,097,152
  unsigned short* attn    = (unsigned short*)(W + 94445568);     // 16,777,216 -> total 111,222,784

  // prep
  cast_f32_bf16<<<6144, 256, 0, stream>>>(x, x_bf, 1572864);
  cast_f32_bf16<<<768,  256, 0, stream>>>(Wih_f, wihcat, 196608);
  cast_f32_bf16<<<768,  256, 0, stream>>>(Wih_b, wihcat + 786432, 196608);
  cast_f32_bf16<<<512,  256, 0, stream>>>(W3, w3bf, 131072);
  pack_w1 <<<128, 256, 0, stream>>>(W1, w1p);
  pack_bias<<<2, 1024, 0, stream>>>(bih_f, bhh_f, bih_b, bhh_b, bc);

  // xg = x @ [Wih_f;Wih_b]^T + bias  -> scan-layout xgp (omode=2)
  gemm_abt<<<dim3(16, 64, 1), 256, 0, stream>>>(x_bf, 768, 0, wihcat, 768, 0, bc,
                                                xgp, 0, 0, 8192, 2048, 768, 2);
  // BiLSTM scan
  lstm_scan<<<16, 256, 0, stream>>>(xgp, Whh_f, Whh_b, mbox, hcat, hT);

  // qp/kp: hcat[:, :512] @ W1pack^T -> qk fp32 [8192][64]
  gemm_abt<<<dim3(1, 64, 1), 256, 0, stream>>>(hcat, 1024, 0, w1p, 512, 0, nullptr,
                                               qk, 64, 0, 8192, 64, 512, 0);
  // scores + softmax -> attn bf16
  attn_scores<<<8192, 256, 0, stream>>>(qk, W2, mask, attn);

  // context = attn @ h (per b): A=attn[b], B=hT[b] (512x1024) -> hcat[:, 512:]
  gemm_abt<<<dim3(4, 8, 8), 256, 0, stream>>>(attn, 1024, 1048576, hT, 1024, 524288, nullptr,
                                              (void*)(hcat + 512), 1024, 1048576, 1024, 512, 1024, 1);
  // y = [h|ctx] @ W3^T + b3 -> d_out fp32
  gemm_abt<<<dim3(4, 64, 1), 256, 0, stream>>>(hcat, 1024, 0, w3bf, 1024, 0, b3,
                                               (float*)d_out, 512, 0, 8192, 512, 1024, 0);
}

// Round 9
// 1716.871 us; speedup vs baseline: 1.2320x; 1.2320x over previous
//
#include <hip/hip_runtime.h>

typedef __attribute__((ext_vector_type(4))) float  f32x4;
typedef __attribute__((ext_vector_type(8))) short  short8;
typedef __attribute__((ext_vector_type(4))) int    i32x4;
typedef __attribute__((ext_vector_type(2))) int    i32x2;

#define LOG2E 1.4426950408889634f

__device__ __forceinline__ float fexp2(float x){ float r; asm("v_exp_f32 %0, %1" : "=v"(r) : "v"(x)); return r; }
__device__ __forceinline__ float frcp (float x){ float r; asm("v_rcp_f32 %0, %1" : "=v"(r) : "v"(x)); return r; }
__device__ __forceinline__ float fsigmoid(float x){ return frcp(1.f + fexp2(-LOG2E*x)); }
__device__ __forceinline__ float ftanhf (float x){ return 1.f - 2.f*frcp(1.f + fexp2(2.f*LOG2E*x)); }

__device__ __forceinline__ unsigned short f2bf(float f){
  unsigned u = __builtin_bit_cast(unsigned, f);
  u = u + 0x7FFFu + ((u >> 16) & 1u);
  return (unsigned short)(u >> 16);
}
__device__ __forceinline__ float bf2f(unsigned short h){
  unsigned u = ((unsigned)h) << 16;
  return __builtin_bit_cast(float, u);
}

// ---------------- fused prep ----------------
// blocks [0,6144): x cast; [6144,6912): Wih_f; [6912,7680): Wih_b; [7680,8192): W3;
// [8192,8320): pack_w1; [8320,8328): pack_bias.
__global__ __launch_bounds__(256) void prep_fused(
    const float* __restrict__ x,     unsigned short* __restrict__ x_bf,
    const float* __restrict__ Wih_f, const float* __restrict__ Wih_b,
    unsigned short* __restrict__ wihcat,
    const float* __restrict__ W3,    unsigned short* __restrict__ w3bf,
    const float* __restrict__ W1,    unsigned short* __restrict__ w1p,
    const float* __restrict__ bif, const float* __restrict__ bhf,
    const float* __restrict__ bib, const float* __restrict__ bhb,
    float* __restrict__ bc)
{
  const int bid = blockIdx.x, tid = threadIdx.x;
  if (bid < 8192){
    const float* s; unsigned short* d; int i;
    if (bid < 6144)      { s = x;     d = x_bf;            i = bid * 256 + tid; }
    else if (bid < 6912) { s = Wih_f; d = wihcat;          i = (bid - 6144) * 256 + tid; }
    else if (bid < 7680) { s = Wih_b; d = wihcat + 786432; i = (bid - 6912) * 256 + tid; }
    else                 { s = W3;    d = w3bf;            i = (bid - 7680) * 256 + tid; }
    float4 f = ((const float4*)s)[i];
    uint2 o;
    o.x = (unsigned)f2bf(f.x) | ((unsigned)f2bf(f.y) << 16);
    o.y = (unsigned)f2bf(f.z) | ((unsigned)f2bf(f.w) << 16);
    ((uint2*)d)[i] = o;
  } else if (bid < 8320){
    int i = (bid - 8192) * 256 + tid;           // 0..32767
    int r = i >> 9, c = i & 511;
    float v = 0.f;
    if (r < 10) v = W1[r * 1024 + c];
    else if (r >= 16 && r < 26) v = W1[(r - 16) * 1024 + 512 + c];
    w1p[i] = f2bf(v);
  } else {
    int i = (bid - 8320) * 256 + tid;           // 0..2047
    if (i < 1024) bc[i] = bif[i] + bhf[i];
    else          bc[i] = bib[i - 1024] + bhb[i - 1024];
  }
}

// ---------------- generic bf16 GEMM: C[M,N] = A[M,K] @ B[N,K]^T (+bias) ----------------
// omode: 0 = f32 out, 1 = bf16 out, 2 = bf16 scan-layout scatter (xgp[d][g][t][b][u][gate])
__global__ __launch_bounds__(256) void gemm_abt(
    const unsigned short* __restrict__ A, long lda, long sAz,
    const unsigned short* __restrict__ B, long ldb, long sBz,
    const float* __restrict__ bias,
    void* __restrict__ Cv, long ldc, long sCz,
    int M, int N, int K, int omode)
{
  __shared__ __align__(16) unsigned short As[128 * 40];
  __shared__ __align__(16) unsigned short Bs[128 * 40];
  const int tid = threadIdx.x;
  const int m0 = blockIdx.y * 128;
  const int n0 = blockIdx.x * 128;
  const long z = blockIdx.z;
  A += z * sAz; B += z * sBz;
  const int w = tid >> 6, l = tid & 63;
  const int wm = (w >> 1) * 64, wn = (w & 1) * 64;
  const int lm = l & 15, lq = l >> 4;
  f32x4 acc[4][4] = {};
  const int sr = tid >> 1;
  const int sk = (tid & 1) * 16;
  const unsigned short* Aptr = A + (long)(m0 + sr) * lda + sk;
  const unsigned short* Bptr = B + (long)(n0 + sr) * ldb + sk;
  const bool bvalid = (n0 + sr) < N;
  const int KB = K >> 5;
  for (int kb = 0; kb < KB; ++kb){
    i32x4 av0 = *(const i32x4*)(Aptr);
    i32x4 av1 = *(const i32x4*)(Aptr + 8);
    i32x4 bv0 = {0,0,0,0}, bv1 = {0,0,0,0};
    if (bvalid){ bv0 = *(const i32x4*)(Bptr); bv1 = *(const i32x4*)(Bptr + 8); }
    Aptr += 32; Bptr += 32;
    __syncthreads();
    *(i32x4*)&As[sr * 40 + sk] = av0;  *(i32x4*)&As[sr * 40 + sk + 8] = av1;
    *(i32x4*)&Bs[sr * 40 + sk] = bv0;  *(i32x4*)&Bs[sr * 40 + sk + 8] = bv1;
    __syncthreads();
    const int koff = lq * 8;
    short8 af[4], bf[4];
    #pragma unroll
    for (int mt = 0; mt < 4; ++mt) af[mt] = *(short8*)&As[(wm + mt * 16 + lm) * 40 + koff];
    #pragma unroll
    for (int nt = 0; nt < 4; ++nt) bf[nt] = *(short8*)&Bs[(wn + nt * 16 + lm) * 40 + koff];
    #pragma unroll
    for (int mt = 0; mt < 4; ++mt)
      #pragma unroll
      for (int nt = 0; nt < 4; ++nt)
        acc[mt][nt] = __builtin_amdgcn_mfma_f32_16x16x32_bf16(af[mt], bf[nt], acc[mt][nt], 0, 0, 0);
  }
  #pragma unroll
  for (int mt = 0; mt < 4; ++mt){
    const int mbase = m0 + wm + mt * 16 + lq * 4;
    #pragma unroll
    for (int nt = 0; nt < 4; ++nt){
      const int n = n0 + wn + nt * 16 + lm;
      if (n < N){
        const float bv = bias ? bias[n] : 0.f;
        #pragma unroll
        for (int r = 0; r < 4; ++r){
          const float v = acc[mt][nt][r] + bv;
          const int m = mbase + r;
          if (omode == 2){
            const int b = m >> 10, tt = m & 1023;
            const int dd = n >> 10, gate = (n >> 8) & 3, unit = n & 255;
            const int gg = unit >> 5, u = unit & 31;
            const long idx = (long)(dd * 8 + gg) * 1048576 + (long)tt * 1024 + b * 128 + u * 4 + gate;
            ((unsigned short*)Cv)[idx] = f2bf(v);
          } else {
            const long idx = z * sCz + (long)m * ldc + n;
            if (omode == 1) ((unsigned short*)Cv)[idx] = f2bf(v);
            else            ((float*)Cv)[idx] = v;
          }
        }
      }
    }
  }
}

// ---------------- LSTM scan v9: R7 exchange, zero output work in the loop ----------------
// 16 blocks x 256 threads. block = (dir d, 32-unit slice g). Wave w = gate w.
// Quarter polls (wave w = batches 2w,2w+1) + ping-pong rounds, exactly as R7.
// The ONLY store per step is the 8B tagged publish; hcat/hT are reconstructed
// post-scan from hexd by repack() -> no dump bursts, minimal per-block jitter
// (straggler coupling: each step completes at the max over 8 producers).
__global__ __launch_bounds__(256) void lstm_scan(
    const unsigned short* __restrict__ xgp,  // [d][g][t][b][u][gate] bf16
    const float* __restrict__ Whh_f, const float* __restrict__ Whh_b,
    unsigned long long* __restrict__ hexd)   // [2][1024][8][128] tagged qwords
{
  const int d  = blockIdx.x & 1;
  const int g  = blockIdx.x >> 1;          // 0..7
  const int tid = threadIdx.x;
  const int w  = tid >> 6;                 // gate / poll quarter
  const int l  = tid & 63;
  const int lm = l & 15;
  const int lq = l >> 4;
  const float* Whh = d ? Whh_b : Whh_f;

  __shared__ __align__(16) unsigned short hbuf[8 * 264];     // shared [b][264]
  __shared__ float gbuf[4][32][9];                           // [gate][j][b pad9]

  // resident B fragments: wave w = gate w; rows w*256 + g*32 + nt*16 + lm; k = kt*32+lq*8
  short8 bfr[2][8];
  #pragma unroll
  for (int nt = 0; nt < 2; ++nt){
    const float* wr = Whh + (long)(w * 256 + g * 32 + nt * 16 + lm) * 256 + lq * 8;
    #pragma unroll
    for (int kt = 0; kt < 8; ++kt){
      float4 f0 = *(const float4*)(wr + kt * 32);
      float4 f1 = *(const float4*)(wr + kt * 32 + 4);
      i32x4 p;
      p.x = (unsigned)f2bf(f0.x) | ((unsigned)f2bf(f0.y) << 16);
      p.y = (unsigned)f2bf(f0.z) | ((unsigned)f2bf(f0.w) << 16);
      p.z = (unsigned)f2bf(f1.x) | ((unsigned)f2bf(f1.y) << 16);
      p.w = (unsigned)f2bf(f1.z) | ((unsigned)f2bf(f1.w) << 16);
      bfr[nt][kt] = __builtin_bit_cast(short8, p);
    }
  }

  const int gb = tid >> 5;        // b (0..7)
  const int gj = tid & 31;        // unit local to slice
  float c_state = 0.f;

  const unsigned short* xbase = xgp + (long)(d * 8 + g) * 1048576 + gb * 128 + gj * 4;
  i32x2 xcur = *(const i32x2*)(xbase + (long)(d ? 1023 : 0) * 1024);

  for (int t = 0; t < 1024; ++t){
    // pipelined bias load for t+1 (plain, compiler-tracked; fenced before poll asm)
    i32x2 xnew;
    {
      const int tn = (t < 1023) ? (t + 1) : t;
      const int t_xn = d ? (1023 - tn) : tn;
      xnew = *(const i32x2*)(xbase + (long)t_xn * 1024);
    }
    f32x4 acc0 = {0.f,0.f,0.f,0.f}, acc1 = {0.f,0.f,0.f,0.f};
    if (t > 0){
      const int tag = 0x5A000000 + (t - 1);
      const char* pb0 = (const char*)(hexd + (long)(d * 1024 + (t - 1)) * 1024)
                        + (2 * w) * 1024 + l * 16;
      const char* pb1 = pb0 + 1024;
      i32x4 a0, a1, b0, b1;
      asm volatile("global_load_dwordx4 %0, %1, off sc0 sc1" : "=v"(a0) : "v"(pb0) : "memory");
      asm volatile("global_load_dwordx4 %0, %1, off sc0 sc1" : "=v"(a1) : "v"(pb1) : "memory");
      asm volatile("global_load_dwordx4 %0, %1, off sc0 sc1" : "=v"(b0) : "v"(pb0) : "memory");
      asm volatile("global_load_dwordx4 %0, %1, off sc0 sc1" : "=v"(b1) : "v"(pb1) : "memory");
      bool useA = false;
      int tries = 0;
      for (;;){
        asm volatile("s_waitcnt vmcnt(2)" : "+v"(a0), "+v"(a1) :: "memory");
        if (__all((int)((a0.x == tag) && (a0.z == tag) && (a1.x == tag) && (a1.z == tag)))){
          useA = true; break;
        }
        asm volatile("s_waitcnt vmcnt(0)" : "+v"(b0), "+v"(b1) :: "memory");
        if (__all((int)((b0.x == tag) && (b0.z == tag) && (b1.x == tag) && (b1.z == tag)))){
          useA = false; break;
        }
        if (++tries >= 32768){ useA = false; break; }
        asm volatile("global_load_dwordx4 %0, %1, off sc0 sc1" : "=v"(a0) : "v"(pb0) : "memory");
        asm volatile("global_load_dwordx4 %0, %1, off sc0 sc1" : "=v"(a1) : "v"(pb1) : "memory");
        asm volatile("global_load_dwordx4 %0, %1, off sc0 sc1" : "=v"(b0) : "v"(pb0) : "memory");
        asm volatile("global_load_dwordx4 %0, %1, off sc0 sc1" : "=v"(b1) : "v"(pb1) : "memory");
      }
      // drain stragglers before register reuse / LDS scatter
      asm volatile("s_waitcnt vmcnt(0)" : "+v"(b0), "+v"(b1) :: "memory");
      const i32x4 r0 = useA ? a0 : b0;
      const i32x4 r1 = useA ? a1 : b1;
      i32x2 p0; p0.x = r0.y; p0.y = r0.w;
      i32x2 p1; p1.x = r1.y; p1.y = r1.w;
      *(i32x2*)&hbuf[(2 * w)     * 264 + l * 4] = p0;
      *(i32x2*)&hbuf[(2 * w + 1) * 264 + l * 4] = p1;
    }
    __syncthreads();   // B1: hbuf complete (all quarters)
    if (t > 0){
      #pragma unroll
      for (int kt = 0; kt < 8; ++kt){
        short8 af = *(const short8*)&hbuf[(lm & 7) * 264 + kt * 32 + lq * 8];
        acc0 = __builtin_amdgcn_mfma_f32_16x16x32_bf16(af, bfr[0][kt], acc0, 0, 0, 0);
        acc1 = __builtin_amdgcn_mfma_f32_16x16x32_bf16(af, bfr[1][kt], acc1, 0, 0, 0);
      }
    }
    // C[b=lq*4+r][j=nt*16+lm] -> gbuf[w][j][b]
    if (l < 32){
      #pragma unroll
      for (int r = 0; r < 4; ++r){
        gbuf[w][lm][lq * 4 + r]      = acc0[r];
        gbuf[w][16 + lm][lq * 4 + r] = acc1[r];
      }
    }
    __syncthreads();   // B2: gbuf visible; also protects hbuf reuse next step
    {
      const float gi = gbuf[0][gj][gb] + bf2f((unsigned short)((unsigned)xcur.x & 0xFFFFu));
      const float gf = gbuf[1][gj][gb] + bf2f((unsigned short)((unsigned)xcur.x >> 16));
      const float gG = gbuf[2][gj][gb] + bf2f((unsigned short)((unsigned)xcur.y & 0xFFFFu));
      const float go = gbuf[3][gj][gb] + bf2f((unsigned short)((unsigned)xcur.y >> 16));
      c_state = fsigmoid(gf) * c_state + fsigmoid(gi) * ftanhf(gG);
      const float h = fsigmoid(go) * ftanhf(c_state);
      const unsigned short hb16 = f2bf(h);
      // publish: the ONLY store in the loop
      const int hp = __shfl_xor((int)hb16, 1);
      if (!(gj & 1)){
        i32x2 st;
        st.x = 0x5A000000 + t;
        st.y = (int)(((unsigned)hb16) | (((unsigned)hp) << 16));
        unsigned long long* sp = hexd + (long)(d * 1024 + t) * 1024 + gb * 128 + g * 16 + (gj >> 1);
        asm volatile("global_store_dwordx2 %0, %1, off sc0 sc1" :: "v"(sp), "v"(st) : "memory");
      }
    }
    xcur = xnew;
  }
}

// ---------------- post-scan repack: hexd -> hcat (cols 0..511) + hT ----------------
// hexd qword (d,t, b*128+p) payload hi-dword = (h[u=2p] | h[u=2p+1]<<16).
// block = (d, b, t-tile of 32). Phase 1: coalesced qword reads -> hcat dwords + LDS tile.
// Phase 2: LDS transpose -> hT dwords (t-pairs packed).
__global__ __launch_bounds__(256) void repack(
    const unsigned long long* __restrict__ hexd,
    unsigned* __restrict__ hcat32,   // [8][1024][512] dwords
    unsigned* __restrict__ hT32)     // [8][512][512] dwords
{
  const int bid = blockIdx.x, tid = threadIdx.x;
  const int d  = bid >> 8;
  const int b  = (bid >> 5) & 7;
  const int t0 = (bid & 31) * 32;
  __shared__ unsigned tile[32 * 132];   // [t_loc][p] pad
  #pragma unroll
  for (int k = 0; k < 16; ++k){
    const int idx = k * 256 + tid;          // 0..4095
    const int t_loc = idx >> 7, p = idx & 127;
    const int t = t0 + t_loc;
    const unsigned long long q = hexd[((long)(d * 1024 + t)) * 1024 + b * 128 + p];
    const unsigned y = (unsigned)(q >> 32);
    const int t_x = d ? (1023 - t) : t;
    hcat32[((long)b * 1024 + t_x) * 512 + d * 128 + p] = y;
    tile[t_loc * 132 + p] = y;
  }
  __syncthreads();
  const int txB = d ? (992 - t0) : t0;     // 32-aligned t_x base of this tile
  #pragma unroll
  for (int k = 0; k < 16; ++k){
    const int idx = k * 256 + tid;          // 0..4095
    const int u_loc = idx >> 4, td = idx & 15;
    const int p = u_loc >> 1, half = (u_loc & 1) * 16;
    int ta, tb;
    if (d){ ta = 31 - 2 * td; tb = 30 - 2 * td; }
    else  { ta = 2 * td;      tb = 2 * td + 1; }
    const unsigned va = (tile[ta * 132 + p] >> half) & 0xFFFFu;
    const unsigned vb = (tile[tb * 132 + p] >> half) & 0xFFFFu;
    hT32[((long)b * 512 + d * 256 + u_loc) * 512 + (txB >> 1) + td] = va | (vb << 16);
  }
}

// ---------------- attention scores + softmax ----------------
__global__ __launch_bounds__(256) void attn_scores(
    const float* __restrict__ qk,   // [8192][64]: qp at cols 0..9, kp at cols 16..25
    const float* __restrict__ W2,   // [10]
    const int*   __restrict__ mask, // [8][1024]
    unsigned short* __restrict__ attn) // [8][1024][1024] bf16
{
  const int bt = blockIdx.x;
  const int b = bt >> 10;
  const int tid = threadIdx.x;
  __shared__ float red[256];
  float qv[10], w2[10];
  const float* qrow = qk + (long)bt * 64;
  #pragma unroll
  for (int x = 0; x < 10; ++x){ qv[x] = qrow[x]; w2[x] = W2[x]; }
  float sv[4];
  float smax = -3.4e38f;
  #pragma unroll
  for (int uu = 0; uu < 4; ++uu){
    const int u = tid + uu * 256;
    const float* krow = qk + (long)(b * 1024 + u) * 64 + 16;
    float s = 0.f;
    #pragma unroll
    for (int x = 0; x < 10; ++x) s += w2[x] * ftanhf(qv[x] + krow[x]);
    if (mask[b * 1024 + u] == 0) s = -3.0e38f;
    sv[uu] = s;
    smax = fmaxf(smax, s);
  }
  red[tid] = smax; __syncthreads();
  for (int off = 128; off > 0; off >>= 1){
    if (tid < off) red[tid] = fmaxf(red[tid], red[tid + off]);
    __syncthreads();
  }
  const float mx = red[0]; __syncthreads();
  float ev[4]; float lsum = 0.f;
  #pragma unroll
  for (int uu = 0; uu < 4; ++uu){ ev[uu] = fexp2((sv[uu] - mx) * LOG2E); lsum += ev[uu]; }
  red[tid] = lsum; __syncthreads();
  for (int off = 128; off > 0; off >>= 1){
    if (tid < off) red[tid] = red[tid] + red[tid + off];
    __syncthreads();
  }
  const float inv = frcp(red[0]);
  #pragma unroll
  for (int uu = 0; uu < 4; ++uu)
    attn[(long)bt * 1024 + tid + uu * 256] = f2bf(ev[uu] * inv);
}

// ---------------- launch ----------------
extern "C" void kernel_launch(void* const* d_in, const int* in_sizes, int n_in,
                              void* d_out, int out_size, void* d_ws, size_t ws_size,
                              hipStream_t stream) {
  (void)in_sizes; (void)n_in; (void)out_size; (void)ws_size;
  const float* x     = (const float*)d_in[0];
  const int*   mask  = (const int*)d_in[1];
  const float* Wih_f = (const float*)d_in[3];
  const float* Whh_f = (const float*)d_in[4];
  const float* bih_f = (const float*)d_in[5];
  const float* bhh_f = (const float*)d_in[6];
  const float* Wih_b = (const float*)d_in[7];
  const float* Whh_b = (const float*)d_in[8];
  const float* bih_b = (const float*)d_in[9];
  const float* bhh_b = (const float*)d_in[10];
  const float* W1    = (const float*)d_in[11];
  const float* W2    = (const float*)d_in[12];
  const float* W3    = (const float*)d_in[13];
  const float* b3    = (const float*)d_in[14];

  char* W = (char*)d_ws;
  unsigned short* x_bf    = (unsigned short*)(W + 0);            // 12,582,912
  unsigned short* wihcat  = (unsigned short*)(W + 12582912);     //  3,145,728
  unsigned short* w3bf    = (unsigned short*)(W + 15728640);     //  1,048,576
  unsigned short* w1p     = (unsigned short*)(W + 16777216);     //     65,536
  float*          bc      = (float*)        (W + 16842752);      //      8,192
  unsigned short* xgp     = (unsigned short*)(W + 16850944);     // 33,554,432
  unsigned long long* hexd= (unsigned long long*)(W + 50405376); // 16,777,216
  unsigned short* hcat    = (unsigned short*)(W + 67182592);     // 16,777,216
  unsigned short* hT      = (unsigned short*)(W + 83959808);     //  8,388,608
  float*          qk      = (float*)        (W + 92348416);      //  2,097,152
  unsigned short* attn    = (unsigned short*)(W + 94445568);     // 16,777,216 -> total 111,222,784

  // fused prep
  prep_fused<<<8328, 256, 0, stream>>>(x, x_bf, Wih_f, Wih_b, wihcat, W3, w3bf, W1, w1p,
                                       bih_f, bhh_f, bih_b, bhh_b, bc);

  // xg = x @ [Wih_f;Wih_b]^T + bias  -> scan-layout xgp (omode=2)
  gemm_abt<<<dim3(16, 64, 1), 256, 0, stream>>>(x_bf, 768, 0, wihcat, 768, 0, bc,
                                                xgp, 0, 0, 8192, 2048, 768, 2);
  // BiLSTM scan (publish-only loop)
  lstm_scan<<<16, 256, 0, stream>>>(xgp, Whh_f, Whh_b, hexd);

  // rebuild hcat (cols 0..511) + hT from the exchange buffer
  repack<<<512, 256, 0, stream>>>(hexd, (unsigned*)hcat, (unsigned*)hT);

  // qp/kp: hcat[:, :512] @ W1pack^T -> qk fp32 [8192][64]
  gemm_abt<<<dim3(1, 64, 1), 256, 0, stream>>>(hcat, 1024, 0, w1p, 512, 0, nullptr,
                                               qk, 64, 0, 8192, 64, 512, 0);
  // scores + softmax -> attn bf16
  attn_scores<<<8192, 256, 0, stream>>>(qk, W2, mask, attn);

  // context = attn @ h (per b): A=attn[b], B=hT[b] (512x1024) -> hcat[:, 512:]
  gemm_abt<<<dim3(4, 8, 8), 256, 0, stream>>>(attn, 1024, 1048576, hT, 1024, 524288, nullptr,
                                              (void*)(hcat + 512), 1024, 1048576, 1024, 512, 1024, 1);
  // y = [h|ctx] @ W3^T + b3 -> d_out fp32
  gemm_abt<<<dim3(4, 64, 1), 256, 0, stream>>>(hcat, 1024, 0, w3bf, 1024, 0, b3,
                                               (float*)d_out, 512, 0, 8192, 512, 1024, 0);
}